// Round 1
// baseline (718.566 us; speedup 1.0000x reference)
//
#include <hip/hip_runtime.h>

// Problem constants
static constexpr int Nn_ = 32, Cc_ = 64, Hh_ = 64, Ww_ = 64;
static constexpr int K_ = 512;
static constexpr int HW_ = Hh_ * Ww_;             // 4096
static constexpr int CHW_ = Cc_ * HW_;            // 262144
static constexpr int T_ = Nn_ * Hh_ * Ww_;        // 131072 tokens
static constexpr int OUT_ELEMS = Nn_ * Cc_ * Hh_ * Ww_;  // 8388608
// d_out layout: [out][codebook_new (32768)][N_new (512)][m_new (32768)]
static constexpr int OFF_CB = OUT_ELEMS;
static constexpr int OFF_N  = OUT_ELEMS + 32768;
static constexpr int OFF_M  = OUT_ELEMS + 32768 + 512;

// ws layout (floats): single fused accumulator, zeroed by k_zero each launch.
// [0, 32768)       psum[k][c]  (global fp32 atomics from k_assign epilogue)
// [32768, 33280)   pcnt[k]
static constexpr int WS_PCNT  = K_ * Cc_;         // 32768
static constexpr int WS_TOTAL = WS_PCNT + K_;     // 33280 floats
static constexpr int ZERO4    = WS_TOTAL / 4;     // 8320 float4 stores

// K0: zero the fused stats accumulator (must precede k_assign's atomics;
// stream order guarantees it). ~130KB -> ~2us.
__global__ __launch_bounds__(256) void k_zero(float* __restrict__ ws) {
    int i = blockIdx.x * 256 + threadIdx.x;
    if (i < ZERO4) ((float4*)ws)[i] = make_float4(0.f, 0.f, 0.f, 0.f);
}

// K1: register-tiled fp32 GEMM (no fp32 MFMA on CDNA4), 8x8 acc/thread.
// 16 b128 LDS reads per 256 FMA = 1 B/FMA -> 4.3 GB ds_read -> 62-82us LDS
// floor vs 54.6us FMA floor. Occupancy LDS-capped at 2 blocks/CU (2 waves/
// SIMD) -> latency hiding is ILP: unroll 4 + launch_bounds(256,2) frees a
// 256-VGPR budget. Argmin update is float-strict-< (4 ops/cand vs 7 for u64
// pack); scan order ascending k so first-min tie-break matches np.argmin;
// u64 lexicographic pack only at the cross-thread reduce. cnorm for all 512
// codewords hoisted to one per-block pass (cb is L2-hot).
// Epilogue fuses the EMA stats: per-block scatter of xs into psum/pcnt via
// fire-and-forget global fp32 atomics (8192+128 per block), overlapped
// across blocks with the GEMM phases of other blocks. Replaces the whole
// k_stats kernel (33.5MB x re-read + 8.4M LDS atomics + 4.2MB partials).
__global__ __launch_bounds__(256, 2) void k_assign(const float* __restrict__ x,
                                                   const float* __restrict__ cb,
                                                   float* __restrict__ ws,
                                                   float* __restrict__ out) {
    __shared__ alignas(16) float xs[64][132];   // [channel][token 0..127]
    __shared__ alignas(16) float cs[128][68];   // [codeword-in-tile][channel]
    __shared__ float cnorm512[512];
    __shared__ int bi_s[128];

    const int b    = blockIdx.x;        // 0..1023: rows 2b, 2b+1
    const int tid  = threadIdx.x;
    const int mg   = tid & 15;          // token-group
    const int ng   = tid >> 4;          // codeword-group
    const int lane = tid & 63;
    const int wv   = tid >> 6;
    const int row0 = 2 * b, row1 = 2 * b + 1;
    const int xb0 = (row0 >> 6) * CHW_ + (row0 & 63) * Ww_;
    const int xb1 = (row1 >> 6) * CHW_ + (row1 & 63) * Ww_;

    // Stage xs[c][t]: 2048 float4, coalesced global reads.
#pragma unroll
    for (int stp = 0; stp < 8; ++stp) {
        int e = stp * 256 + tid;        // float4 id
        int c = e >> 5, s = e & 31;     // s = token-quad 0..31
        int r = s >> 4, wq = s & 15;
        float4 v = *(const float4*)(x + (r ? xb1 : xb0) + c * HW_ + 4 * wq);
        *(float4*)&xs[c][4 * s] = v;
    }

    // cnorm for ALL 512 codewords, once per block (cb L2-hot: 128KB).
    // Visible to epilogues via the post-stage __syncthreads in kt=0.
    for (int r = tid; r < 512; r += 256) {
        const float4* cr = (const float4*)(cb + r * 64);
        float a = 0.f;
#pragma unroll
        for (int i = 0; i < 16; ++i) {
            float4 v = cr[i];
            a = fmaf(v.x, v.x, a); a = fmaf(v.y, v.y, a);
            a = fmaf(v.z, v.z, a); a = fmaf(v.w, v.w, a);
        }
        cnorm512[r] = a;
    }

    float bdA[4], bdB[4];               // tokens 4mg+mi / 64+4mg+mi
    int   bkA[4], bkB[4];
#pragma unroll
    for (int i = 0; i < 4; ++i) {
        bdA[i] = __int_as_float(0x7f800000);   // +inf
        bdB[i] = __int_as_float(0x7f800000);
        bkA[i] = 0; bkB[i] = 0;
    }

#pragma unroll 1
    for (int kt = 0; kt < 4; ++kt) {
        // Stage cs[r][c] for codewords kt*128..+127 (coalesced float4).
        // cs reads of kt-1 done (post-c4 sync); epilogue touches regs only.
#pragma unroll
        for (int stp = 0; stp < 8; ++stp) {
            int e = stp * 256 + tid;
            int rr = e >> 4, cq = e & 15;
            float4 v = *(const float4*)(cb + (kt * 128 + rr) * 64 + 4 * cq);
            *(float4*)&cs[rr][4 * cq] = v;
        }
        __syncthreads();                 // cs (and, kt=0: xs/cnorm512) ready

        // 4 x 4x4 sub-tiles: (tokA,tokB) x (cwA,cwB)
        float aAA[4][4], aAB[4][4], aBA[4][4], aBB[4][4];
#pragma unroll
        for (int a = 0; a < 4; ++a)
#pragma unroll
            for (int c2 = 0; c2 < 4; ++c2) {
                aAA[a][c2] = 0.f; aAB[a][c2] = 0.f;
                aBA[a][c2] = 0.f; aBB[a][c2] = 0.f;
            }

#pragma unroll 4
        for (int c4 = 0; c4 < 64; c4 += 4) {
            float xA[4][4], xB[4][4], cA[4][4], cB[4][4];
#pragma unroll
            for (int i = 0; i < 4; ++i) {
                *(float4*)xA[i] = *(const float4*)&xs[c4 + i][4 * mg];        // xA[i][mi]
                *(float4*)xB[i] = *(const float4*)&xs[c4 + i][64 + 4 * mg];
            }
#pragma unroll
            for (int j = 0; j < 4; ++j) {
                *(float4*)cA[j] = *(const float4*)&cs[4 * ng + j][c4];        // cA[j][i]
                *(float4*)cB[j] = *(const float4*)&cs[64 + 4 * ng + j][c4];
            }
#pragma unroll
            for (int j = 0; j < 4; ++j)
#pragma unroll
                for (int mi = 0; mi < 4; ++mi)
#pragma unroll
                    for (int i = 0; i < 4; ++i) {
                        aAA[mi][j] = fmaf(xA[i][mi], cA[j][i], aAA[mi][j]);
                        aAB[mi][j] = fmaf(xA[i][mi], cB[j][i], aAB[mi][j]);
                        aBA[mi][j] = fmaf(xB[i][mi], cA[j][i], aBA[mi][j]);
                        aBB[mi][j] = fmaf(xB[i][mi], cB[j][i], aBB[mi][j]);
                    }
        }
        __syncthreads();                 // cs reads done (next kt restages)

        // d = cnorm - 2*dot (token-constant |x|^2 dropped: argmin-invariant)
        // Strict < keeps FIRST min; candidate order ascending in k:
        // A-half codewords (kb..kb+3), then B-half (kb+64..kb+67), kt asc.
        const int kb = kt * 128 + 4 * ng;
#pragma unroll
        for (int j = 0; j < 4; ++j) {
            float cn = cnorm512[kb + j];
            int   kk = kb + j;
#pragma unroll
            for (int mi = 0; mi < 4; ++mi) {
                float dA = fmaf(-2.0f, aAA[mi][j], cn);
                if (dA < bdA[mi]) { bdA[mi] = dA; bkA[mi] = kk; }
                float dB = fmaf(-2.0f, aBA[mi][j], cn);
                if (dB < bdB[mi]) { bdB[mi] = dB; bkB[mi] = kk; }
            }
        }
#pragma unroll
        for (int j = 0; j < 4; ++j) {
            float cn = cnorm512[kb + 64 + j];
            int   kk = kb + 64 + j;
#pragma unroll
            for (int mi = 0; mi < 4; ++mi) {
                float dA = fmaf(-2.0f, aAB[mi][j], cn);
                if (dA < bdA[mi]) { bdA[mi] = dA; bkA[mi] = kk; }
                float dB = fmaf(-2.0f, aBB[mi][j], cn);
                if (dB < bdB[mi]) { bdB[mi] = dB; bkB[mi] = kk; }
            }
        }
    }

    // Cross-thread argmin: pack (d,k) -> u64 (monotone flip); lexicographic
    // u64 min == (min d, then min k) == np first-min. red overlays cs.
    unsigned long long* red = (unsigned long long*)&cs[0][0];   // [128][17]
#pragma unroll
    for (int mi = 0; mi < 4; ++mi) {
        unsigned uA = __float_as_uint(bdA[mi]);
        uA = (uA & 0x80000000u) ? ~uA : (uA | 0x80000000u);
        red[(4 * mg + mi) * 17 + ng] = ((unsigned long long)uA << 32) | (unsigned)bkA[mi];
        unsigned uB = __float_as_uint(bdB[mi]);
        uB = (uB & 0x80000000u) ? ~uB : (uB | 0x80000000u);
        red[(64 + 4 * mg + mi) * 17 + ng] = ((unsigned long long)uB << 32) | (unsigned)bkB[mi];
    }
    __syncthreads();
    if (tid < 128) {
        unsigned long long bm = red[tid * 17 + 0];
#pragma unroll
        for (int j = 1; j < 16; ++j) {
            unsigned long long v = red[tid * 17 + j];
            if (v < bm) bm = v;
        }
        bi_s[tid] = (int)(bm & 0xffffffffu);
    }
    __syncthreads();

    // Fused EMA stats: scatter xs into psum[k][c] / pcnt[k] via global
    // fp32 atomics. Thread = (token tid>>1, channel-half tid&1): xs column
    // walk is 2-lane-per-bank (free); 32 scalar atomics/thread.
    {
        const int tt = tid >> 1;
        const int hf = tid & 1;
        const int kk = bi_s[tt];
        float* pb = ws + kk * 64 + 32 * hf;
#pragma unroll
        for (int i = 0; i < 32; ++i) {
            atomicAdd(pb + i, xs[32 * hf + i][tt]);
        }
        if (tid < 128) atomicAdd(ws + WS_PCNT + bi_s[tid], 1.0f);
    }
    __syncthreads();                     // xs reads done before qt overlay

    // q gather + transpose: qt overlays xs
    float (*qt)[132] = xs;
#pragma unroll
    for (int jj = 0; jj < 32; ++jj) {
        int tt = wv * 32 + jj;
        qt[lane][tt] = cb[bi_s[tt] * 64 + lane];     // one 256B row per load
    }
    __syncthreads();
#pragma unroll
    for (int r = 0; r < 2; ++r)
#pragma unroll
        for (int j = 0; j < 16; ++j) {
            int c = wv * 16 + j;
            out[(r ? xb1 : xb0) + c * HW_ + lane] = qt[c][64 * r + lane];  // coalesced
        }
}

// K3: finalize EMA states and codebook_new straight from the fused
// accumulator (no slice reduction). i = k*64+c, fully coalesced.
__global__ __launch_bounds__(256) void k_final(const float* __restrict__ Ns,
                                               const float* __restrict__ ms,
                                               const float* __restrict__ ws,
                                               float* __restrict__ out) {
    int i = blockIdx.x * 256 + threadIdx.x;   // 0..32767
    int k = i >> 6, c = i & 63;

    float s   = ws[i];                 // psum[k][c]
    float cnt = ws[WS_PCNT + k];       // pcnt[k] (broadcast within wave)

    const float gamma = 0.99f;
    const float omg   = (float)(1.0 - 0.99);

    bool occ = cnt > 0.0f;
    float Nv = Ns[k];
    float Nnew = occ ? (Nv * gamma + cnt * omg) : Nv;

    float mv = ms[i];
    float mnew = occ ? (mv * gamma + s * omg) : mv;

    out[OFF_CB + i] = mnew / Nnew;
    out[OFF_M  + i] = mnew;
    if (c == 0) out[OFF_N + k] = Nnew;
}

extern "C" void kernel_launch(void* const* d_in, const int* in_sizes, int n_in,
                              void* d_out, int out_size, void* d_ws, size_t ws_size,
                              hipStream_t stream) {
    const float* x  = (const float*)d_in[0];
    const float* cb = (const float*)d_in[1];
    const float* Ns = (const float*)d_in[2];
    const float* ms = (const float*)d_in[3];
    float* out = (float*)d_out;
    float* ws  = (float*)d_ws;

    hipLaunchKernelGGL(k_zero,   dim3((ZERO4 + 255) / 256), dim3(256), 0, stream, ws);
    hipLaunchKernelGGL(k_assign, dim3(1024),                dim3(256), 0, stream, x, cb, ws, out);
    hipLaunchKernelGGL(k_final,  dim3(32768 / 256),         dim3(256), 0, stream, Ns, ms, ws, out);
}

// Round 2
// 277.050 us; speedup vs baseline: 2.5936x; 2.5936x over previous
//
#include <hip/hip_runtime.h>

// Problem constants
static constexpr int Nn_ = 32, Cc_ = 64, Hh_ = 64, Ww_ = 64;
static constexpr int K_ = 512;
static constexpr int HW_ = Hh_ * Ww_;             // 4096
static constexpr int CHW_ = Cc_ * HW_;            // 262144
static constexpr int T_ = Nn_ * Hh_ * Ww_;        // 131072 tokens
static constexpr int OUT_ELEMS = Nn_ * Cc_ * Hh_ * Ww_;  // 8388608
// d_out layout: [out][codebook_new (32768)][N_new (512)][m_new (32768)]
static constexpr int OFF_CB = OUT_ELEMS;
static constexpr int OFF_N  = OUT_ELEMS + 32768;
static constexpr int OFF_M  = OUT_ELEMS + 32768 + 512;

// ws layout (floats):
// [0, T_)                 idx per token (int)
// [WS_PART, +P*SLICE_F)   P dense partial slices: [psum 512*64][pcnt 512]
static constexpr int WS_IDX   = 0;
static constexpr int WS_PART  = T_;
static constexpr int SLICE_F  = K_ * Cc_ + K_;    // 33280 floats/slice

// K1: register-tiled fp32 GEMM (no fp32 MFMA on CDNA4), 8x8 acc/thread.
// 16 b128 LDS reads per 256 FMA = 1 B/FMA -> 4.3 GB ds_read -> 62-82us LDS
// floor vs 54.6us FMA floor. LDS 71KB caps occupancy at 2 blocks/CU -> the
// allocator has a free 256-VGPR budget (launch_bounds(256,2)); latency
// hiding is ILP (unroll 4). Argmin is float-strict-< (4 ops/cand vs 7 for
// u64 pack), scan ascending k so first-min tie-break matches np.argmin;
// u64 lexicographic pack only at the cross-thread reduce. cnorm for all
// 512 codewords hoisted to one per-block pass (cb is L2-hot).
// R1 lesson: NO global atomics (8.4M fp32 atomics = 298MB writes, 4.7x
// slowdown). Stats go through idx + the conflict-structured k_stats below.
__global__ __launch_bounds__(256, 2) void k_assign(const float* __restrict__ x,
                                                   const float* __restrict__ cb,
                                                   float* __restrict__ ws,
                                                   float* __restrict__ out) {
    __shared__ alignas(16) float xs[64][132];   // [channel][token 0..127]
    __shared__ alignas(16) float cs[128][68];   // [codeword-in-tile][channel]
    __shared__ float cnorm512[512];
    __shared__ int bi_s[128];

    const int b    = blockIdx.x;        // 0..1023: rows 2b, 2b+1
    const int tid  = threadIdx.x;
    const int mg   = tid & 15;          // token-group
    const int ng   = tid >> 4;          // codeword-group
    const int lane = tid & 63;
    const int wv   = tid >> 6;
    const int row0 = 2 * b, row1 = 2 * b + 1;
    const int xb0 = (row0 >> 6) * CHW_ + (row0 & 63) * Ww_;
    const int xb1 = (row1 >> 6) * CHW_ + (row1 & 63) * Ww_;

    // Stage xs[c][t]: 2048 float4, coalesced global reads.
#pragma unroll
    for (int stp = 0; stp < 8; ++stp) {
        int e = stp * 256 + tid;        // float4 id
        int c = e >> 5, s = e & 31;     // s = token-quad 0..31
        int r = s >> 4, wq = s & 15;
        float4 v = *(const float4*)(x + (r ? xb1 : xb0) + c * HW_ + 4 * wq);
        *(float4*)&xs[c][4 * s] = v;
    }

    // cnorm for ALL 512 codewords, once per block (cb L2-hot: 128KB).
    // Visible to consumers via the post-stage __syncthreads in kt=0.
    for (int r = tid; r < 512; r += 256) {
        const float4* cr = (const float4*)(cb + r * 64);
        float a = 0.f;
#pragma unroll
        for (int i = 0; i < 16; ++i) {
            float4 v = cr[i];
            a = fmaf(v.x, v.x, a); a = fmaf(v.y, v.y, a);
            a = fmaf(v.z, v.z, a); a = fmaf(v.w, v.w, a);
        }
        cnorm512[r] = a;
    }

    float bdA[4], bdB[4];               // tokens 4mg+mi / 64+4mg+mi
    int   bkA[4], bkB[4];
#pragma unroll
    for (int i = 0; i < 4; ++i) {
        bdA[i] = __int_as_float(0x7f800000);   // +inf
        bdB[i] = __int_as_float(0x7f800000);
        bkA[i] = 0; bkB[i] = 0;
    }

#pragma unroll 1
    for (int kt = 0; kt < 4; ++kt) {
        // Stage cs[r][c] for codewords kt*128..+127 (coalesced float4).
        // cs reads of kt-1 done (post-c4 sync); argmin tail is reg-only.
#pragma unroll
        for (int stp = 0; stp < 8; ++stp) {
            int e = stp * 256 + tid;
            int rr = e >> 4, cq = e & 15;
            float4 v = *(const float4*)(cb + (kt * 128 + rr) * 64 + 4 * cq);
            *(float4*)&cs[rr][4 * cq] = v;
        }
        __syncthreads();                 // cs (and, kt=0: xs/cnorm512) ready

        // 4 x 4x4 sub-tiles: (tokA,tokB) x (cwA,cwB)
        float aAA[4][4], aAB[4][4], aBA[4][4], aBB[4][4];
#pragma unroll
        for (int a = 0; a < 4; ++a)
#pragma unroll
            for (int c2 = 0; c2 < 4; ++c2) {
                aAA[a][c2] = 0.f; aAB[a][c2] = 0.f;
                aBA[a][c2] = 0.f; aBB[a][c2] = 0.f;
            }

#pragma unroll 4
        for (int c4 = 0; c4 < 64; c4 += 4) {
            float xA[4][4], xB[4][4], cA[4][4], cB[4][4];
#pragma unroll
            for (int i = 0; i < 4; ++i) {
                *(float4*)xA[i] = *(const float4*)&xs[c4 + i][4 * mg];        // xA[i][mi]
                *(float4*)xB[i] = *(const float4*)&xs[c4 + i][64 + 4 * mg];
            }
#pragma unroll
            for (int j = 0; j < 4; ++j) {
                *(float4*)cA[j] = *(const float4*)&cs[4 * ng + j][c4];        // cA[j][i]
                *(float4*)cB[j] = *(const float4*)&cs[64 + 4 * ng + j][c4];
            }
#pragma unroll
            for (int j = 0; j < 4; ++j)
#pragma unroll
                for (int mi = 0; mi < 4; ++mi)
#pragma unroll
                    for (int i = 0; i < 4; ++i) {
                        aAA[mi][j] = fmaf(xA[i][mi], cA[j][i], aAA[mi][j]);
                        aAB[mi][j] = fmaf(xA[i][mi], cB[j][i], aAB[mi][j]);
                        aBA[mi][j] = fmaf(xB[i][mi], cA[j][i], aBA[mi][j]);
                        aBB[mi][j] = fmaf(xB[i][mi], cB[j][i], aBB[mi][j]);
                    }
        }
        __syncthreads();                 // cs reads done (next kt restages)

        // d = cnorm - 2*dot (token-constant |x|^2 dropped: argmin-invariant)
        // Strict < keeps FIRST min; candidate order ascending in k.
        const int kb = kt * 128 + 4 * ng;
#pragma unroll
        for (int j = 0; j < 4; ++j) {
            float cn = cnorm512[kb + j];
            int   kk = kb + j;
#pragma unroll
            for (int mi = 0; mi < 4; ++mi) {
                float dA = fmaf(-2.0f, aAA[mi][j], cn);
                if (dA < bdA[mi]) { bdA[mi] = dA; bkA[mi] = kk; }
                float dB = fmaf(-2.0f, aBA[mi][j], cn);
                if (dB < bdB[mi]) { bdB[mi] = dB; bkB[mi] = kk; }
            }
        }
#pragma unroll
        for (int j = 0; j < 4; ++j) {
            float cn = cnorm512[kb + 64 + j];
            int   kk = kb + 64 + j;
#pragma unroll
            for (int mi = 0; mi < 4; ++mi) {
                float dA = fmaf(-2.0f, aAB[mi][j], cn);
                if (dA < bdA[mi]) { bdA[mi] = dA; bkA[mi] = kk; }
                float dB = fmaf(-2.0f, aBB[mi][j], cn);
                if (dB < bdB[mi]) { bdB[mi] = dB; bkB[mi] = kk; }
            }
        }
    }

    // Cross-thread argmin: pack (d,k) -> u64 (monotone flip); lexicographic
    // u64 min == (min d, then min k) == np first-min. red overlays cs.
    unsigned long long* red = (unsigned long long*)&cs[0][0];   // [128][17]
#pragma unroll
    for (int mi = 0; mi < 4; ++mi) {
        unsigned uA = __float_as_uint(bdA[mi]);
        uA = (uA & 0x80000000u) ? ~uA : (uA | 0x80000000u);
        red[(4 * mg + mi) * 17 + ng] = ((unsigned long long)uA << 32) | (unsigned)bkA[mi];
        unsigned uB = __float_as_uint(bdB[mi]);
        uB = (uB & 0x80000000u) ? ~uB : (uB | 0x80000000u);
        red[(64 + 4 * mg + mi) * 17 + ng] = ((unsigned long long)uB << 32) | (unsigned)bkB[mi];
    }
    __syncthreads();
    if (tid < 128) {
        unsigned long long bm = red[tid * 17 + 0];
#pragma unroll
        for (int j = 1; j < 16; ++j) {
            unsigned long long v = red[tid * 17 + j];
            if (v < bm) bm = v;
        }
        int bi = (int)(bm & 0xffffffffu);
        ((int*)(ws + WS_IDX))[128 * b + tid] = bi;   // coalesced; == n*HW+hw order
        bi_s[tid] = bi;
    }
    __syncthreads();

    // q gather + transpose: qt overlays xs (xs reads done)
    float (*qt)[132] = xs;
#pragma unroll
    for (int jj = 0; jj < 32; ++jj) {
        int tt = wv * 32 + jj;
        qt[lane][tt] = cb[bi_s[tt] * 64 + lane];     // one 256B row per load
    }
    __syncthreads();
#pragma unroll
    for (int r = 0; r < 2; ++r)
#pragma unroll
        for (int j = 0; j < 16; ++j) {
            int c = wv * 16 + j;
            out[(r ? xb1 : xb0) + c * HW_ + lane] = qt[c][64 * r + lane];  // coalesced
        }
}

// K2: conflict-structured stats. Block = (image s, token chunk); holds the
// FULL psum[512][64] in LDS (128KB, fits gfx950's 160KB). Per token, ONE
// wave-wide ds_add: 64 lanes -> psum[k][0..63], consecutive addresses,
// 2 lanes/bank (free), zero same-address collisions. 131K full-width atomic
// instrs total vs round-0's 8.4M scalar-lane scatter (the ~85us culprit).
// x staged via padded LDS transpose xt[64][65] (65*t === t mod 32 -> both
// the 4-scalar column writes and the row reads are conflict-free).
// Each block writes an EXCLUSIVE dense partial slice -> no atomics anywhere
// past LDS. P partials chosen from ws_size (34MB at P=256, degrades to 4.8MB
// at P=32, which round-0's workspace already held).
__global__ __launch_bounds__(256) void k_stats(const float* __restrict__ x,
                                               const float* __restrict__ ws_ro,
                                               float* __restrict__ ws,
                                               int lgn) {
    __shared__ float psum[512][64];     // 128 KB
    __shared__ float xt[64][65];        // 16.6 KB, padded stride
    __shared__ float pcnt[512];
    __shared__ int   idx_s[512];

    const int tid  = threadIdx.x;
    const int bid  = blockIdx.x;
    const int s    = bid >> lgn;
    const int chunk = bid & ((1 << lgn) - 1);
    const int ngroups = 8 >> lgn;
    const int wv = tid >> 6, lane = tid & 63;

    const float4 z = make_float4(0.f, 0.f, 0.f, 0.f);
#pragma unroll
    for (int i = 0; i < 32; ++i) ((float4*)psum)[i * 256 + tid] = z;
    pcnt[tid] = 0.f; pcnt[tid + 256] = 0.f;

    const int* __restrict__ idxg = (const int*)ws_ro;   // WS_IDX == 0

    for (int g = 0; g < ngroups; ++g) {
        const int tbase = chunk * (4096 >> lgn) + (g << 9);   // in-slice token base
        __syncthreads();   // g=0: zeroing done; g>0: prev scatter's idx_s reads done
        int k0 = idxg[s * 4096 + tbase + tid];
        int k1 = idxg[s * 4096 + tbase + tid + 256];
        idx_s[tid] = k0;
        idx_s[tid + 256] = k1;
        atomicAdd(&pcnt[k0], 1.0f);     // own-loaded values; no sync needed
        atomicAdd(&pcnt[k1], 1.0f);

        for (int sc = 0; sc < 8; ++sc) {
            __syncthreads();            // xt free (prev sub-chunk reads done)
            // stage 64 tokens x 64 ch: coalesced 256B-per-row global float4,
            // transposed into xt (4 scalar column writes, conflict-free)
#pragma unroll
            for (int it = 0; it < 4; ++it) {
                int e = it * 256 + tid;
                int c = e >> 4, tq = e & 15;
                float4 v = *(const float4*)(x + s * CHW_ + c * HW_ + tbase + sc * 64 + 4 * tq);
                xt[4 * tq + 0][c] = v.x;
                xt[4 * tq + 1][c] = v.y;
                xt[4 * tq + 2][c] = v.z;
                xt[4 * tq + 3][c] = v.w;
            }
            __syncthreads();            // xt + idx_s ready
            // wave w owns tokens [16w,16w+16): one full-width ds_add each
#pragma unroll
            for (int i = 0; i < 16; ++i) {
                int tok = wv * 16 + i;
                int k = idx_s[sc * 64 + tok];               // wave-uniform
                atomicAdd(&psum[k][lane], xt[tok][lane]);   // 64 consecutive
            }
        }
    }
    __syncthreads();                     // all ds_adds drained (lgkmcnt)
    float* pb = ws + WS_PART + bid * SLICE_F;
#pragma unroll
    for (int i = 0; i < 32; ++i)
        ((float4*)pb)[i * 256 + tid] = ((float4*)psum)[i * 256 + tid];
    pb[32768 + tid]       = pcnt[tid];
    pb[32768 + tid + 256] = pcnt[tid + 256];
}

// K3: reduce P exclusive partials, finalize EMA states + codebook_new.
// i = k*64+c: psum loads coalesced; cnt load is wave-uniform (broadcast).
__global__ __launch_bounds__(256) void k_final(const float* __restrict__ Ns,
                                               const float* __restrict__ ms,
                                               const float* __restrict__ ws,
                                               float* __restrict__ out,
                                               int P) {
    int i = blockIdx.x * 256 + threadIdx.x;   // 0..32767
    int k = i >> 6, c = i & 63;

    const float* base = ws + WS_PART;
    float s = 0.f, cnt = 0.f;
#pragma unroll 4
    for (int p = 0; p < P; ++p) {
        s   += base[p * SLICE_F + i];
        cnt += base[p * SLICE_F + 32768 + k];
    }

    const float gamma = 0.99f;
    const float omg   = (float)(1.0 - 0.99);

    bool occ = cnt > 0.0f;
    float Nv = Ns[k];
    float Nnew = occ ? (Nv * gamma + cnt * omg) : Nv;

    float mv = ms[i];
    float mnew = occ ? (mv * gamma + s * omg) : mv;

    out[OFF_CB + i] = mnew / Nnew;
    out[OFF_M  + i] = mnew;
    if (c == 0) out[OFF_N + k] = Nnew;
}

extern "C" void kernel_launch(void* const* d_in, const int* in_sizes, int n_in,
                              void* d_out, int out_size, void* d_ws, size_t ws_size,
                              hipStream_t stream) {
    const float* x  = (const float*)d_in[0];
    const float* cb = (const float*)d_in[1];
    const float* Ns = (const float*)d_in[2];
    const float* ms = (const float*)d_in[3];
    float* out = (float*)d_out;
    float* ws  = (float*)d_ws;

    // Partial-slice count from workspace size: P = 32<<lgn, need
    // (T_ + P*SLICE_F)*4 bytes. P=256 -> 34.6MB; P=32 -> 4.8MB (round-0 fit).
    int lgn = 3;
    while (lgn > 0 &&
           (size_t)(WS_PART + ((size_t)(32 << lgn)) * SLICE_F) * 4 > ws_size)
        --lgn;
    int P = 32 << lgn;

    hipLaunchKernelGGL(k_assign, dim3(1024), dim3(256), 0, stream, x, cb, ws, out);
    hipLaunchKernelGGL(k_stats,  dim3(P),    dim3(256), 0, stream, x, ws, ws, lgn);
    hipLaunchKernelGGL(k_final,  dim3(128),  dim3(256), 0, stream, Ns, ms, ws, out, P);
}

// Round 3
// 268.006 us; speedup vs baseline: 2.6812x; 1.0337x over previous
//
#include <hip/hip_runtime.h>

// Problem constants
static constexpr int Nn_ = 32, Cc_ = 64, Hh_ = 64, Ww_ = 64;
static constexpr int K_ = 512;
static constexpr int HW_ = Hh_ * Ww_;             // 4096
static constexpr int CHW_ = Cc_ * HW_;            // 262144
static constexpr int T_ = Nn_ * Hh_ * Ww_;        // 131072 tokens
static constexpr int OUT_ELEMS = Nn_ * Cc_ * Hh_ * Ww_;  // 8388608
// d_out layout: [out][codebook_new (32768)][N_new (512)][m_new (32768)]
static constexpr int OFF_CB = OUT_ELEMS;
static constexpr int OFF_N  = OUT_ELEMS + 32768;
static constexpr int OFF_M  = OUT_ELEMS + 32768 + 512;

// ws layout (floats):
// [0, T_)            idx per token (int), written by k_assign
// [WS_ACC, +33280)   merged accumulator: [psum 512*64][pcnt 512]
//                    zeroed by k_zero, built by k_stats via wave-wide
//                    global atomics (P=1 -> k_final reads 133KB, not 34MB)
static constexpr int WS_IDX  = 0;
static constexpr int WS_ACC  = T_;
static constexpr int ACC_CNT = 32768;             // offset of pcnt inside acc
static constexpr int ACC_F   = K_ * Cc_ + K_;     // 33280 floats
static constexpr int ZERO4   = ACC_F / 4;         // 8320 float4 stores

// K0: zero the merged accumulator each replay (graph-safe, ~2us).
__global__ __launch_bounds__(256) void k_zero(float* __restrict__ ws) {
    int i = blockIdx.x * 256 + threadIdx.x;
    if (i < ZERO4) ((float4*)(ws + WS_ACC))[i] = make_float4(0.f, 0.f, 0.f, 0.f);
}

// K1: register-tiled fp32 GEMM (no fp32 MFMA on CDNA4), 8x8 acc/thread.
// UNCHANGED from R2 (the control): 138us, VALUBusy 65%, ~82us LDS-bound
// floor (1 B/FMA ds_read at ~12cy/b128, 2 rounds of 2 blocks/CU).
__global__ __launch_bounds__(256, 2) void k_assign(const float* __restrict__ x,
                                                   const float* __restrict__ cb,
                                                   float* __restrict__ ws,
                                                   float* __restrict__ out) {
    __shared__ alignas(16) float xs[64][132];   // [channel][token 0..127]
    __shared__ alignas(16) float cs[128][68];   // [codeword-in-tile][channel]
    __shared__ float cnorm512[512];
    __shared__ int bi_s[128];

    const int b    = blockIdx.x;        // 0..1023: rows 2b, 2b+1
    const int tid  = threadIdx.x;
    const int mg   = tid & 15;          // token-group
    const int ng   = tid >> 4;          // codeword-group
    const int lane = tid & 63;
    const int wv   = tid >> 6;
    const int row0 = 2 * b, row1 = 2 * b + 1;
    const int xb0 = (row0 >> 6) * CHW_ + (row0 & 63) * Ww_;
    const int xb1 = (row1 >> 6) * CHW_ + (row1 & 63) * Ww_;

    // Stage xs[c][t]: 2048 float4, coalesced global reads.
#pragma unroll
    for (int stp = 0; stp < 8; ++stp) {
        int e = stp * 256 + tid;        // float4 id
        int c = e >> 5, s = e & 31;     // s = token-quad 0..31
        int r = s >> 4, wq = s & 15;
        float4 v = *(const float4*)(x + (r ? xb1 : xb0) + c * HW_ + 4 * wq);
        *(float4*)&xs[c][4 * s] = v;
    }

    // cnorm for ALL 512 codewords, once per block (cb L2-hot: 128KB).
    for (int r = tid; r < 512; r += 256) {
        const float4* cr = (const float4*)(cb + r * 64);
        float a = 0.f;
#pragma unroll
        for (int i = 0; i < 16; ++i) {
            float4 v = cr[i];
            a = fmaf(v.x, v.x, a); a = fmaf(v.y, v.y, a);
            a = fmaf(v.z, v.z, a); a = fmaf(v.w, v.w, a);
        }
        cnorm512[r] = a;
    }

    float bdA[4], bdB[4];               // tokens 4mg+mi / 64+4mg+mi
    int   bkA[4], bkB[4];
#pragma unroll
    for (int i = 0; i < 4; ++i) {
        bdA[i] = __int_as_float(0x7f800000);   // +inf
        bdB[i] = __int_as_float(0x7f800000);
        bkA[i] = 0; bkB[i] = 0;
    }

#pragma unroll 1
    for (int kt = 0; kt < 4; ++kt) {
        // Stage cs[r][c] for codewords kt*128..+127 (coalesced float4).
#pragma unroll
        for (int stp = 0; stp < 8; ++stp) {
            int e = stp * 256 + tid;
            int rr = e >> 4, cq = e & 15;
            float4 v = *(const float4*)(cb + (kt * 128 + rr) * 64 + 4 * cq);
            *(float4*)&cs[rr][4 * cq] = v;
        }
        __syncthreads();                 // cs (and, kt=0: xs/cnorm512) ready

        // 4 x 4x4 sub-tiles: (tokA,tokB) x (cwA,cwB)
        float aAA[4][4], aAB[4][4], aBA[4][4], aBB[4][4];
#pragma unroll
        for (int a = 0; a < 4; ++a)
#pragma unroll
            for (int c2 = 0; c2 < 4; ++c2) {
                aAA[a][c2] = 0.f; aAB[a][c2] = 0.f;
                aBA[a][c2] = 0.f; aBB[a][c2] = 0.f;
            }

#pragma unroll 4
        for (int c4 = 0; c4 < 64; c4 += 4) {
            float xA[4][4], xB[4][4], cA[4][4], cB[4][4];
#pragma unroll
            for (int i = 0; i < 4; ++i) {
                *(float4*)xA[i] = *(const float4*)&xs[c4 + i][4 * mg];        // xA[i][mi]
                *(float4*)xB[i] = *(const float4*)&xs[c4 + i][64 + 4 * mg];
            }
#pragma unroll
            for (int j = 0; j < 4; ++j) {
                *(float4*)cA[j] = *(const float4*)&cs[4 * ng + j][c4];        // cA[j][i]
                *(float4*)cB[j] = *(const float4*)&cs[64 + 4 * ng + j][c4];
            }
#pragma unroll
            for (int j = 0; j < 4; ++j)
#pragma unroll
                for (int mi = 0; mi < 4; ++mi)
#pragma unroll
                    for (int i = 0; i < 4; ++i) {
                        aAA[mi][j] = fmaf(xA[i][mi], cA[j][i], aAA[mi][j]);
                        aAB[mi][j] = fmaf(xA[i][mi], cB[j][i], aAB[mi][j]);
                        aBA[mi][j] = fmaf(xB[i][mi], cA[j][i], aBA[mi][j]);
                        aBB[mi][j] = fmaf(xB[i][mi], cB[j][i], aBB[mi][j]);
                    }
        }
        __syncthreads();                 // cs reads done (next kt restages)

        // d = cnorm - 2*dot (token-constant |x|^2 dropped: argmin-invariant)
        // Strict < keeps FIRST min; candidate order ascending in k.
        const int kb = kt * 128 + 4 * ng;
#pragma unroll
        for (int j = 0; j < 4; ++j) {
            float cn = cnorm512[kb + j];
            int   kk = kb + j;
#pragma unroll
            for (int mi = 0; mi < 4; ++mi) {
                float dA = fmaf(-2.0f, aAA[mi][j], cn);
                if (dA < bdA[mi]) { bdA[mi] = dA; bkA[mi] = kk; }
                float dB = fmaf(-2.0f, aBA[mi][j], cn);
                if (dB < bdB[mi]) { bdB[mi] = dB; bkB[mi] = kk; }
            }
        }
#pragma unroll
        for (int j = 0; j < 4; ++j) {
            float cn = cnorm512[kb + 64 + j];
            int   kk = kb + 64 + j;
#pragma unroll
            for (int mi = 0; mi < 4; ++mi) {
                float dA = fmaf(-2.0f, aAB[mi][j], cn);
                if (dA < bdA[mi]) { bdA[mi] = dA; bkA[mi] = kk; }
                float dB = fmaf(-2.0f, aBB[mi][j], cn);
                if (dB < bdB[mi]) { bdB[mi] = dB; bkB[mi] = kk; }
            }
        }
    }

    // Cross-thread argmin: pack (d,k) -> u64 (monotone flip); lexicographic
    // u64 min == (min d, then min k) == np first-min. red overlays cs.
    unsigned long long* red = (unsigned long long*)&cs[0][0];   // [128][17]
#pragma unroll
    for (int mi = 0; mi < 4; ++mi) {
        unsigned uA = __float_as_uint(bdA[mi]);
        uA = (uA & 0x80000000u) ? ~uA : (uA | 0x80000000u);
        red[(4 * mg + mi) * 17 + ng] = ((unsigned long long)uA << 32) | (unsigned)bkA[mi];
        unsigned uB = __float_as_uint(bdB[mi]);
        uB = (uB & 0x80000000u) ? ~uB : (uB | 0x80000000u);
        red[(64 + 4 * mg + mi) * 17 + ng] = ((unsigned long long)uB << 32) | (unsigned)bkB[mi];
    }
    __syncthreads();
    if (tid < 128) {
        unsigned long long bm = red[tid * 17 + 0];
#pragma unroll
        for (int j = 1; j < 16; ++j) {
            unsigned long long v = red[tid * 17 + j];
            if (v < bm) bm = v;
        }
        int bi = (int)(bm & 0xffffffffu);
        ((int*)(ws + WS_IDX))[128 * b + tid] = bi;   // coalesced; == n*HW+hw order
        bi_s[tid] = bi;
    }
    __syncthreads();

    // q gather + transpose: qt overlays xs (xs reads done)
    float (*qt)[132] = xs;
#pragma unroll
    for (int jj = 0; jj < 32; ++jj) {
        int tt = wv * 32 + jj;
        qt[lane][tt] = cb[bi_s[tt] * 64 + lane];     // one 256B row per load
    }
    __syncthreads();
#pragma unroll
    for (int r = 0; r < 2; ++r)
#pragma unroll
        for (int j = 0; j < 16; ++j) {
            int c = wv * 16 + j;
            out[(r ? xb1 : xb0) + c * HW_ + lane] = qt[c][64 * r + lane];  // coalesced
        }
}

// K2: conflict-structured stats, merged writeback. Block = (image s, chunk
// of 512 tokens); full psum[512][64] in LDS (128KB). Per token ONE wave-wide
// ds_add (64 consecutive addresses, 2 lanes/bank = free, no collisions).
// Writeback: only OCCUPIED rows (~324/512 by Poisson) as wave-wide global
// atomicAdd over 64 consecutive floats -> 4 L2-line RMWs per instr, ~83K
// wave-ops chip-wide into a 133KB L2-resident region (HBM write ~133KB).
// This is the anti-R1 shape: R1's 298MB came from 64 RANDOM lines/instr.
// No exclusive partials -> no 34MB write + no 34MB k_final re-read.
__global__ __launch_bounds__(256) void k_stats(const float* __restrict__ x,
                                               const float* __restrict__ ws_ro,
                                               float* __restrict__ ws) {
    __shared__ float psum[512][64];     // 128 KB
    __shared__ float xt[64][65];        // 16.6 KB, padded stride
    __shared__ float pcnt[512];
    __shared__ int   idx_s[512];

    const int tid   = threadIdx.x;
    const int bid   = blockIdx.x;
    const int s     = bid >> 3;
    const int chunk = bid & 7;
    const int tbase = chunk * 512;
    const int wv = tid >> 6, lane = tid & 63;

    const float4 z = make_float4(0.f, 0.f, 0.f, 0.f);
#pragma unroll
    for (int i = 0; i < 32; ++i) ((float4*)psum)[i * 256 + tid] = z;
    pcnt[tid] = 0.f; pcnt[tid + 256] = 0.f;
    __syncthreads();                    // zero done before any atomic lands

    const int* __restrict__ idxg = (const int*)ws_ro;   // WS_IDX == 0
    int k0 = idxg[s * 4096 + tbase + tid];
    int k1 = idxg[s * 4096 + tbase + tid + 256];
    idx_s[tid] = k0;
    idx_s[tid + 256] = k1;
    atomicAdd(&pcnt[k0], 1.0f);         // 512 scattered lane-atomics: cheap
    atomicAdd(&pcnt[k1], 1.0f);

    for (int sc = 0; sc < 8; ++sc) {
        __syncthreads();                // xt free (prev sub-chunk reads done);
                                        // sc=0: also publishes idx_s
        // stage 64 tokens x 64 ch: coalesced 256B-per-row global float4,
        // transposed into xt (16 scalar column writes, 2-way = free)
#pragma unroll
        for (int it = 0; it < 4; ++it) {
            int e = it * 256 + tid;
            int c = e >> 4, tq = e & 15;
            float4 v = *(const float4*)(x + s * CHW_ + c * HW_ + tbase + sc * 64 + 4 * tq);
            xt[4 * tq + 0][c] = v.x;
            xt[4 * tq + 1][c] = v.y;
            xt[4 * tq + 2][c] = v.z;
            xt[4 * tq + 3][c] = v.w;
        }
        __syncthreads();                // xt ready
        // wave w owns tokens [16w,16w+16): one full-width ds_add each
#pragma unroll
        for (int i = 0; i < 16; ++i) {
            int tok = wv * 16 + i;
            int k = idx_s[sc * 64 + tok];               // wave-uniform
            atomicAdd(&psum[k][lane], xt[tok][lane]);   // 64 consecutive
        }
    }
    __syncthreads();                    // all ds_adds drained

    // Merged writeback: occupied rows only; branch is wave-uniform
    // (pcnt[k] is a same-address LDS broadcast).
    float* acc = ws + WS_ACC;
    for (int k = wv; k < 512; k += 4) {
        float pc = pcnt[k];
        if (pc > 0.f)
            atomicAdd(acc + k * 64 + lane, psum[k][lane]);   // 64 consecutive
    }
#pragma unroll
    for (int r = 0; r < 2; ++r) {
        int k2 = r * 256 + tid;
        float pc = pcnt[k2];
        if (pc > 0.f) atomicAdd(acc + ACC_CNT + k2, pc);     // coalesced region
    }
}

// K3: finalize EMA states + codebook_new from the 133KB merged accumulator
// (L2-hot). i = k*64+c: coalesced; cnt load wave-uniform broadcast.
__global__ __launch_bounds__(256) void k_final(const float* __restrict__ Ns,
                                               const float* __restrict__ ms,
                                               const float* __restrict__ ws,
                                               float* __restrict__ out) {
    int i = blockIdx.x * 256 + threadIdx.x;   // 0..32767
    int k = i >> 6, c = i & 63;

    const float* acc = ws + WS_ACC;
    float s   = acc[i];
    float cnt = acc[ACC_CNT + k];

    const float gamma = 0.99f;
    const float omg   = (float)(1.0 - 0.99);

    bool occ = cnt > 0.0f;
    float Nv = Ns[k];
    float Nnew = occ ? (Nv * gamma + cnt * omg) : Nv;

    float mv = ms[i];
    float mnew = occ ? (mv * gamma + s * omg) : mv;

    out[OFF_CB + i] = mnew / Nnew;
    out[OFF_M  + i] = mnew;
    if (c == 0) out[OFF_N + k] = Nnew;
}

extern "C" void kernel_launch(void* const* d_in, const int* in_sizes, int n_in,
                              void* d_out, int out_size, void* d_ws, size_t ws_size,
                              hipStream_t stream) {
    const float* x  = (const float*)d_in[0];
    const float* cb = (const float*)d_in[1];
    const float* Ns = (const float*)d_in[2];
    const float* ms = (const float*)d_in[3];
    float* out = (float*)d_out;
    float* ws  = (float*)d_ws;

    hipLaunchKernelGGL(k_zero,   dim3(33),   dim3(256), 0, stream, ws);
    hipLaunchKernelGGL(k_assign, dim3(1024), dim3(256), 0, stream, x, cb, ws, out);
    hipLaunchKernelGGL(k_stats,  dim3(256),  dim3(256), 0, stream, x, ws, ws);
    hipLaunchKernelGGL(k_final,  dim3(128),  dim3(256), 0, stream, Ns, ms, ws, out);
}

// Round 4
// 217.323 us; speedup vs baseline: 3.3064x; 1.2332x over previous
//
#include <hip/hip_runtime.h>

// Problem constants
static constexpr int Nn_ = 32, Cc_ = 64, Hh_ = 64, Ww_ = 64;
static constexpr int K_ = 512;
static constexpr int HW_ = Hh_ * Ww_;             // 4096
static constexpr int CHW_ = Cc_ * HW_;            // 262144
static constexpr int T_ = Nn_ * Hh_ * Ww_;        // 131072 tokens
static constexpr int OUT_ELEMS = Nn_ * Cc_ * Hh_ * Ww_;  // 8388608
// d_out layout: [out][codebook_new (32768)][N_new (512)][m_new (32768)]
static constexpr int OFF_CB = OUT_ELEMS;
static constexpr int OFF_N  = OUT_ELEMS + 32768;
static constexpr int OFF_M  = OUT_ELEMS + 32768 + 512;

// ws layout (floats): just the merged accumulator now (idx deleted — its
// only consumer, k_stats, is gone).
// [0, 33280)   [psum 512*64][pcnt 512]; zeroed by k_zero each replay,
//              built by k_assign's fused epilogue via wave-wide atomics.
static constexpr int WS_ACC  = 0;
static constexpr int ACC_CNT = 32768;             // offset of pcnt inside acc
static constexpr int ACC_F   = K_ * Cc_ + K_;     // 33280 floats
static constexpr int ZERO4   = ACC_F / 4;         // 8320 float4 stores

// K0: zero the merged accumulator each replay (graph-safe, ~2us).
// Stream order guarantees completion before k_assign's first atomic.
__global__ __launch_bounds__(256) void k_zero(float* __restrict__ ws) {
    int i = blockIdx.x * 256 + threadIdx.x;
    if (i < ZERO4) ((float4*)(ws + WS_ACC))[i] = make_float4(0.f, 0.f, 0.f, 0.f);
}

// K1: register-tiled fp32 GEMM (no fp32 MFMA on CDNA4), 8x8 acc/thread —
// GEMM body UNCHANGED from R2/R3 (the 138us control). New: fused EMA-stats
// epilogue.
//
// R3 post-mortem: separate k_stats ran at 1 wave/SIMD (151KB LDS) -> fully
// latency-exposed main loop ~60us + 33.5MB x re-fetch + re-transpose. But
// k_assign already holds x transposed (xs) and the argmin (bi_s) in LDS.
// Atomic-shape evidence: R1 = per-lane SCATTERED global atomics, 62ns/
// lane-op, catastrophic. R3 writeback = wave-wide CONSECUTIVE atomics,
// ~170ns/wave-op (~3ns/lane-op). So the fused epilogue uses ONE wave-wide
// atomicAdd per token over 64 consecutive floats: 128 wave-ops/block,
// 131K chip-wide (~22us atomic-unit time), fire-and-forget, overlapped
// with other blocks' GEMM phases.
__global__ __launch_bounds__(256, 2) void k_assign(const float* __restrict__ x,
                                                   const float* __restrict__ cb,
                                                   float* __restrict__ ws,
                                                   float* __restrict__ out) {
    __shared__ alignas(16) float xs[64][132];   // [channel][token 0..127]
    __shared__ alignas(16) float cs[128][68];   // [codeword-in-tile][channel]
    __shared__ float cnorm512[512];
    __shared__ int bi_s[128];

    const int b    = blockIdx.x;        // 0..1023: rows 2b, 2b+1
    const int tid  = threadIdx.x;
    const int mg   = tid & 15;          // token-group
    const int ng   = tid >> 4;          // codeword-group
    const int lane = tid & 63;
    const int wv   = tid >> 6;
    const int row0 = 2 * b, row1 = 2 * b + 1;
    const int xb0 = (row0 >> 6) * CHW_ + (row0 & 63) * Ww_;
    const int xb1 = (row1 >> 6) * CHW_ + (row1 & 63) * Ww_;

    // Stage xs[c][t]: 2048 float4, coalesced global reads.
#pragma unroll
    for (int stp = 0; stp < 8; ++stp) {
        int e = stp * 256 + tid;        // float4 id
        int c = e >> 5, s = e & 31;     // s = token-quad 0..31
        int r = s >> 4, wq = s & 15;
        float4 v = *(const float4*)(x + (r ? xb1 : xb0) + c * HW_ + 4 * wq);
        *(float4*)&xs[c][4 * s] = v;
    }

    // cnorm for ALL 512 codewords, once per block (cb L2-hot: 128KB).
    for (int r = tid; r < 512; r += 256) {
        const float4* cr = (const float4*)(cb + r * 64);
        float a = 0.f;
#pragma unroll
        for (int i = 0; i < 16; ++i) {
            float4 v = cr[i];
            a = fmaf(v.x, v.x, a); a = fmaf(v.y, v.y, a);
            a = fmaf(v.z, v.z, a); a = fmaf(v.w, v.w, a);
        }
        cnorm512[r] = a;
    }

    float bdA[4], bdB[4];               // tokens 4mg+mi / 64+4mg+mi
    int   bkA[4], bkB[4];
#pragma unroll
    for (int i = 0; i < 4; ++i) {
        bdA[i] = __int_as_float(0x7f800000);   // +inf
        bdB[i] = __int_as_float(0x7f800000);
        bkA[i] = 0; bkB[i] = 0;
    }

#pragma unroll 1
    for (int kt = 0; kt < 4; ++kt) {
        // Stage cs[r][c] for codewords kt*128..+127 (coalesced float4).
#pragma unroll
        for (int stp = 0; stp < 8; ++stp) {
            int e = stp * 256 + tid;
            int rr = e >> 4, cq = e & 15;
            float4 v = *(const float4*)(cb + (kt * 128 + rr) * 64 + 4 * cq);
            *(float4*)&cs[rr][4 * cq] = v;
        }
        __syncthreads();                 // cs (and, kt=0: xs/cnorm512) ready

        // 4 x 4x4 sub-tiles: (tokA,tokB) x (cwA,cwB)
        float aAA[4][4], aAB[4][4], aBA[4][4], aBB[4][4];
#pragma unroll
        for (int a = 0; a < 4; ++a)
#pragma unroll
            for (int c2 = 0; c2 < 4; ++c2) {
                aAA[a][c2] = 0.f; aAB[a][c2] = 0.f;
                aBA[a][c2] = 0.f; aBB[a][c2] = 0.f;
            }

#pragma unroll 4
        for (int c4 = 0; c4 < 64; c4 += 4) {
            float xA[4][4], xB[4][4], cA[4][4], cB[4][4];
#pragma unroll
            for (int i = 0; i < 4; ++i) {
                *(float4*)xA[i] = *(const float4*)&xs[c4 + i][4 * mg];        // xA[i][mi]
                *(float4*)xB[i] = *(const float4*)&xs[c4 + i][64 + 4 * mg];
            }
#pragma unroll
            for (int j = 0; j < 4; ++j) {
                *(float4*)cA[j] = *(const float4*)&cs[4 * ng + j][c4];        // cA[j][i]
                *(float4*)cB[j] = *(const float4*)&cs[64 + 4 * ng + j][c4];
            }
#pragma unroll
            for (int j = 0; j < 4; ++j)
#pragma unroll
                for (int mi = 0; mi < 4; ++mi)
#pragma unroll
                    for (int i = 0; i < 4; ++i) {
                        aAA[mi][j] = fmaf(xA[i][mi], cA[j][i], aAA[mi][j]);
                        aAB[mi][j] = fmaf(xA[i][mi], cB[j][i], aAB[mi][j]);
                        aBA[mi][j] = fmaf(xB[i][mi], cA[j][i], aBA[mi][j]);
                        aBB[mi][j] = fmaf(xB[i][mi], cB[j][i], aBB[mi][j]);
                    }
        }
        __syncthreads();                 // cs reads done (next kt restages)

        // d = cnorm - 2*dot (token-constant |x|^2 dropped: argmin-invariant)
        // Strict < keeps FIRST min; candidate order ascending in k.
        const int kb = kt * 128 + 4 * ng;
#pragma unroll
        for (int j = 0; j < 4; ++j) {
            float cn = cnorm512[kb + j];
            int   kk = kb + j;
#pragma unroll
            for (int mi = 0; mi < 4; ++mi) {
                float dA = fmaf(-2.0f, aAA[mi][j], cn);
                if (dA < bdA[mi]) { bdA[mi] = dA; bkA[mi] = kk; }
                float dB = fmaf(-2.0f, aBA[mi][j], cn);
                if (dB < bdB[mi]) { bdB[mi] = dB; bkB[mi] = kk; }
            }
        }
#pragma unroll
        for (int j = 0; j < 4; ++j) {
            float cn = cnorm512[kb + 64 + j];
            int   kk = kb + 64 + j;
#pragma unroll
            for (int mi = 0; mi < 4; ++mi) {
                float dA = fmaf(-2.0f, aAB[mi][j], cn);
                if (dA < bdA[mi]) { bdA[mi] = dA; bkA[mi] = kk; }
                float dB = fmaf(-2.0f, aBB[mi][j], cn);
                if (dB < bdB[mi]) { bdB[mi] = dB; bkB[mi] = kk; }
            }
        }
    }

    // Cross-thread argmin: pack (d,k) -> u64 (monotone flip); lexicographic
    // u64 min == (min d, then min k) == np first-min. red overlays cs.
    unsigned long long* red = (unsigned long long*)&cs[0][0];   // [128][17]
#pragma unroll
    for (int mi = 0; mi < 4; ++mi) {
        unsigned uA = __float_as_uint(bdA[mi]);
        uA = (uA & 0x80000000u) ? ~uA : (uA | 0x80000000u);
        red[(4 * mg + mi) * 17 + ng] = ((unsigned long long)uA << 32) | (unsigned)bkA[mi];
        unsigned uB = __float_as_uint(bdB[mi]);
        uB = (uB & 0x80000000u) ? ~uB : (uB | 0x80000000u);
        red[(64 + 4 * mg + mi) * 17 + ng] = ((unsigned long long)uB << 32) | (unsigned)bkB[mi];
    }
    __syncthreads();
    if (tid < 128) {
        unsigned long long bm = red[tid * 17 + 0];
#pragma unroll
        for (int j = 1; j < 16; ++j) {
            unsigned long long v = red[tid * 17 + j];
            if (v < bm) bm = v;
        }
        bi_s[tid] = (int)(bm & 0xffffffffu);
    }
    __syncthreads();

    // Fused EMA stats: one wave-wide atomicAdd per token over 64 CONSECUTIVE
    // floats (HW-coalesced; ~170ns/wave-op per R3 measurement). bi_s[tt] is
    // a wave-uniform LDS broadcast. xs column read is stride-132 (8-way bank
    // alias, ~2.9x ds cost: ~550cy/wave total — negligible). Fire-and-forget:
    // no dependent use, so waves proceed; only end-of-kernel drain waits.
    float* acc = ws + WS_ACC;
#pragma unroll 4
    for (int jj = 0; jj < 32; ++jj) {
        int tt = wv * 32 + jj;
        atomicAdd(acc + bi_s[tt] * 64 + lane, xs[lane][tt]);
    }
    if (tid < 128) atomicAdd(acc + ACC_CNT + bi_s[tid], 1.0f);  // 128 lane-ops
    __syncthreads();                     // xs reads done before qt overlay

    // q gather + transpose: qt overlays xs (xs reads done)
    float (*qt)[132] = xs;
#pragma unroll
    for (int jj = 0; jj < 32; ++jj) {
        int tt = wv * 32 + jj;
        qt[lane][tt] = cb[bi_s[tt] * 64 + lane];     // one 256B row per load
    }
    __syncthreads();
#pragma unroll
    for (int r = 0; r < 2; ++r)
#pragma unroll
        for (int j = 0; j < 16; ++j) {
            int c = wv * 16 + j;
            out[(r ? xb1 : xb0) + c * HW_ + lane] = qt[c][64 * r + lane];  // coalesced
        }
}

// K3: finalize EMA states + codebook_new from the 133KB merged accumulator
// (L2-hot). i = k*64+c: coalesced; cnt load wave-uniform broadcast.
__global__ __launch_bounds__(256) void k_final(const float* __restrict__ Ns,
                                               const float* __restrict__ ms,
                                               const float* __restrict__ ws,
                                               float* __restrict__ out) {
    int i = blockIdx.x * 256 + threadIdx.x;   // 0..32767
    int k = i >> 6, c = i & 63;

    const float* acc = ws + WS_ACC;
    float s   = acc[i];
    float cnt = acc[ACC_CNT + k];

    const float gamma = 0.99f;
    const float omg   = (float)(1.0 - 0.99);

    bool occ = cnt > 0.0f;
    float Nv = Ns[k];
    float Nnew = occ ? (Nv * gamma + cnt * omg) : Nv;

    float mv = ms[i];
    float mnew = occ ? (mv * gamma + s * omg) : mv;

    out[OFF_CB + i] = mnew / Nnew;
    out[OFF_M  + i] = mnew;
    if (c == 0) out[OFF_N + k] = Nnew;
}

extern "C" void kernel_launch(void* const* d_in, const int* in_sizes, int n_in,
                              void* d_out, int out_size, void* d_ws, size_t ws_size,
                              hipStream_t stream) {
    const float* x  = (const float*)d_in[0];
    const float* cb = (const float*)d_in[1];
    const float* Ns = (const float*)d_in[2];
    const float* ms = (const float*)d_in[3];
    float* out = (float*)d_out;
    float* ws  = (float*)d_ws;

    hipLaunchKernelGGL(k_zero,   dim3(33),   dim3(256), 0, stream, ws);
    hipLaunchKernelGGL(k_assign, dim3(1024), dim3(256), 0, stream, x, cb, ws, out);
    hipLaunchKernelGGL(k_final,  dim3(128),  dim3(256), 0, stream, Ns, ms, ws, out);
}